// Round 11
// baseline (365.358 us; speedup 1.0000x reference)
//
#include <hip/hip_runtime.h>
#include <math.h>

#define EPS 1e-8f
#define NB_SORT 256  // blocks in coarse sort phases

#if defined(__has_builtin)
#if __has_builtin(__builtin_amdgcn_sdot4)
#define HAVE_SDOT4 1
#endif
#endif

__device__ __forceinline__ int sdot4i(int a, int b, int c) {
#ifdef HAVE_SDOT4
  return __builtin_amdgcn_sdot4(a, b, c, false);
#else
  return c + ((int)(signed char)(a)) * ((int)(signed char)(b)) +
         ((int)(signed char)(a >> 8)) * ((int)(signed char)(b >> 8)) +
         ((int)(signed char)(a >> 16)) * ((int)(signed char)(b >> 16)) +
         (a >> 24) * (b >> 24);
#endif
}

__device__ __forceinline__ float wave_reduce_sum(float v) {
#pragma unroll
  for (int off = 32; off > 0; off >>= 1)
    v += __shfl_xor(v, off, 64);
  return v;
}

__device__ __forceinline__ float wave_reduce_max(float v) {
#pragma unroll
  for (int off = 32; off > 0; off >>= 1)
    v = fmaxf(v, __shfl_xor(v, off, 64));
  return v;
}

__device__ __forceinline__ float dot4(float4 a, float4 b) {
  return a.x * b.x + a.y * b.y + a.z * b.z + a.w * b.w;
}

__device__ __forceinline__ int clampq(float q) {
  int i = (int)rintf(q);
  return i < -127 ? -127 : (i > 127 ? 127 : i);
}

// ============ CSR build: 2-level bucket sort, LDS atomics only ============
__global__ __launch_bounds__(256) void hist_coarse(const int* __restrict__ dst,
                                                   int* __restrict__ hist_blk,
                                                   int E, int nbuck) {
  __shared__ int lh[1024];
  int t = threadIdx.x, blk = blockIdx.x;
  for (int i = t; i < nbuck; i += 256) lh[i] = 0;
  __syncthreads();
  int ch = (E + NB_SORT - 1) / NB_SORT;
  int lo = blk * ch, hi = min(E, lo + ch);
  for (int e = lo + t; e < hi; e += 256) atomicAdd(&lh[dst[e] >> 6], 1);
  __syncthreads();
  for (int i = t; i < nbuck; i += 256) hist_blk[i * NB_SORT + blk] = lh[i];
}

__global__ __launch_bounds__(256) void scan_local(int* __restrict__ hist,
                                                  int* __restrict__ bsum,
                                                  int nb) {
  __shared__ int tsum[256];
  int t = threadIdx.x;
  int base = blockIdx.x * 1024 + t * 4;
  int v0 = 0, v1 = 0, v2 = 0, v3 = 0;
  if (base + 3 < nb) {
    int4 q = *(const int4*)&hist[base];
    v0 = q.x; v1 = q.y; v2 = q.z; v3 = q.w;
  } else {
    if (base + 0 < nb) v0 = hist[base + 0];
    if (base + 1 < nb) v1 = hist[base + 1];
    if (base + 2 < nb) v2 = hist[base + 2];
  }
  tsum[t] = v0 + v1 + v2 + v3;
  __syncthreads();
  for (int off = 1; off < 256; off <<= 1) {
    int u = 0;
    if (t >= off) u = tsum[t - off];
    __syncthreads();
    if (t >= off) tsum[t] += u;
    __syncthreads();
  }
  int excl = (t == 0) ? 0 : tsum[t - 1];
  int e0 = excl, e1 = excl + v0, e2 = e1 + v1, e3 = e2 + v2;
  if (base + 3 < nb) {
    *(int4*)&hist[base] = make_int4(e0, e1, e2, e3);
  } else {
    if (base + 0 < nb) hist[base + 0] = e0;
    if (base + 1 < nb) hist[base + 1] = e1;
    if (base + 2 < nb) hist[base + 2] = e2;
  }
  if (t == 255) bsum[blockIdx.x] = tsum[255];
}

__global__ __launch_bounds__(256) void scan_bsum(int* __restrict__ bsum,
                                                 int nblk) {
  __shared__ int sh[256];
  int t = threadIdx.x;
  sh[t] = (t < nblk) ? bsum[t] : 0;
  __syncthreads();
  for (int off = 1; off < 256; off <<= 1) {
    int u = 0;
    if (t >= off) u = sh[t - off];
    __syncthreads();
    if (t >= off) sh[t] += u;
    __syncthreads();
  }
  if (t < nblk) bsum[t] = (t == 0) ? 0 : sh[t - 1];
}

__global__ __launch_bounds__(256) void add_bsum(int* __restrict__ hist,
                                                const int* __restrict__ bsum,
                                                int nb) {
  int i = blockIdx.x * blockDim.x + threadIdx.x;
  if (i < nb) hist[i] += bsum[i >> 10];
}

__global__ __launch_bounds__(256) void scatter_coarse(
    const int* __restrict__ src, const int* __restrict__ dst,
    const int* __restrict__ S, int2* __restrict__ epair, int E, int nbuck) {
  __shared__ int lb[1024];
  int t = threadIdx.x, blk = blockIdx.x;
  for (int i = t; i < nbuck; i += 256) lb[i] = S[i * NB_SORT + blk];
  __syncthreads();
  int ch = (E + NB_SORT - 1) / NB_SORT;
  int lo = blk * ch, hi = min(E, lo + ch);
  for (int e = lo + t; e < hi; e += 256) {
    int d = dst[e];
    int pos = atomicAdd(&lb[d >> 6], 1);
    epair[pos] = make_int2(src[e], d);
  }
}

__global__ __launch_bounds__(256) void fine_sort(
    const int2* __restrict__ epair, const int* __restrict__ S,
    int* __restrict__ ssrc, int* __restrict__ endoff, int E, int nbuck,
    int N) {
  __shared__ int fh[64];
  __shared__ int cur[64];
  int b = blockIdx.x, t = threadIdx.x;
  int bstart = S[b * NB_SORT];
  int bend = (b + 1 < nbuck) ? S[(b + 1) * NB_SORT] : E;
  if (t < 64) fh[t] = 0;
  __syncthreads();
  for (int e = bstart + t; e < bend; e += 256)
    atomicAdd(&fh[epair[e].y & 63], 1);
  __syncthreads();
  if (t < 64) {
    int v = fh[t];
    int incl = v;
#pragma unroll
    for (int off = 1; off < 64; off <<= 1) {
      int u = __shfl_up(incl, off, 64);
      if (t >= off) incl += u;
    }
    cur[t] = incl - v;
    int d = b * 64 + t;
    if (d < N) endoff[d] = bstart + incl;
  }
  __syncthreads();
  for (int e = bstart + t; e < bend; e += 256) {
    int2 p = epair[e];
    int pos = atomicAdd(&cur[p.y & 63], 1);
    ssrc[bstart + pos] = p.x;
  }
}

// ============ prep: quantize + node props (norm, scale, L1m) ==============
// nprop = (norm2, scale, L1m, 0); quantization error per edge (s,d) bounded:
// |dot - s_s*s_d*idot| <= 0.5002*(s_s*L1m_d + s_d*L1m_s)
__global__ __launch_bounds__(256) void prep_x(const float* __restrict__ x,
                                              signed char* __restrict__ qx,
                                              float4* __restrict__ nprop,
                                              int N) {
  int node = (int)((blockIdx.x * blockDim.x + threadIdx.x) >> 6);
  int lane = threadIdx.x & 63;
  if (node >= N) return;
  float2 v = *(const float2*)(x + (size_t)node * 128 + lane * 2);
  float ax = fabsf(v.x), ay = fabsf(v.y);
  float mx = wave_reduce_max(fmaxf(ax, ay));
  float l1 = wave_reduce_sum(ax + ay);
  float ss = wave_reduce_sum(v.x * v.x + v.y * v.y);
  float s = mx * (1.0f / 127.0f);
  float inv = (mx > 0.f) ? 127.0f / mx : 0.f;
  int q0 = clampq(v.x * inv), q1 = clampq(v.y * inv);
  unsigned short w = (unsigned short)((q0 & 0xff) | ((q1 & 0xff) << 8));
  ((unsigned short*)(qx + (size_t)node * 128))[lane] = w;
  float l1q = s * wave_reduce_sum((float)(abs(q0) + abs(q1)));
  if (lane == 0)
    nprop[node] = make_float4(sqrtf(ss), s, fmaxf(l1, l1q), 0.f);
}

__global__ __launch_bounds__(256) void prep_h(const float* __restrict__ h,
                                              signed char* __restrict__ qh,
                                              float4* __restrict__ nprop,
                                              int N) {
  int node = (int)((blockIdx.x * blockDim.x + threadIdx.x) >> 6);
  int lane = threadIdx.x & 63;
  if (node >= N) return;
  float4 v = *(const float4*)(h + (size_t)node * 256 + lane * 4);
  float ax = fabsf(v.x), ay = fabsf(v.y), az = fabsf(v.z), aw = fabsf(v.w);
  float mx = wave_reduce_max(fmaxf(fmaxf(ax, ay), fmaxf(az, aw)));
  float l1 = wave_reduce_sum(ax + ay + az + aw);
  float ss = wave_reduce_sum(dot4(v, v));
  float s = mx * (1.0f / 127.0f);
  float inv = (mx > 0.f) ? 127.0f / mx : 0.f;
  int q0 = clampq(v.x * inv), q1 = clampq(v.y * inv);
  int q2 = clampq(v.z * inv), q3 = clampq(v.w * inv);
  int w = (q0 & 0xff) | ((q1 & 0xff) << 8) | ((q2 & 0xff) << 16) | (q3 << 24);
  ((int*)(qh + (size_t)node * 256))[lane] = w;
  float l1q = s * wave_reduce_sum((float)(abs(q0) + abs(q1) + abs(q2) + abs(q3)));
  if (lane == 0)
    nprop[node] = make_float4(sqrtf(ss), s, fmaxf(l1, l1q), 0.f);
}

// ====== conv, lane-per-edge: one 512-thread block per 64-node bucket ======
// 8 waves/block (vs 4) -> ~2x resident waves per CU at the same 18.9 KB LDS:
// more outstanding gathers to hide LLC latency (r10: 22% occupancy, 3.0 TB/s).
// Phase 0: self-loop init of the bucket's agg rows (this block owns all edges
// of these rows, so plain stores + __syncthreads before any atomics is safe).
// Edge phase: lane-per-edge int8 screen against the LDS dst tile, no
// cross-lane reduce; rare screen-passers handled wave-cooperatively (ballot ->
// exact fp32 gather + wave reduce + atomicAdd).
template <int D>
__global__ __launch_bounds__(512) void conv_lpe(
    const float* __restrict__ xf, const signed char* __restrict__ qt,
    const float4* __restrict__ nprop, const int* __restrict__ ssrc,
    const int* __restrict__ endoff, float* __restrict__ agg, int N) {
  constexpr int RB = D + 16;  // padded LDS row bytes
  constexpr int NG = D / 16;  // int4 chunks per row
  constexpr int V = D / 64;   // fp32 elems per lane (exact path)
  __shared__ signed char qtile[64 * RB];
  __shared__ float4 npd[64];
  __shared__ int eoff[65];
  const int tid = threadIdx.x;
  const int lane = tid & 63;
  const int n0 = blockIdx.x * 64;

  if (tid < 65) {
    int idx = n0 - 1 + tid;
    eoff[tid] = (idx < 0) ? 0 : endoff[min(idx, N - 1)];
  }
  if (tid >= 64 && tid < 128) {
    int i = tid - 64;
    int n = n0 + i;
    npd[i] = (n < N) ? nprop[n] : make_float4(0.f, 0.f, 0.f, 0.f);
  }
  for (int j = tid; j < 64 * NG; j += 512) {
    int r = j / NG, c = j % NG;
    int n = n0 + r;
    int4 v = (n < N) ? *(const int4*)(qt + (size_t)n * D + c * 16)
                     : make_int4(0, 0, 0, 0);
    *(int4*)(qtile + r * RB + c * 16) = v;
  }

  // ---- phase 0: self-loop init (8 waves x 8 nodes) ----
  {
    int w = tid >> 6;
    for (int i = w; i < 64; i += 8) {
      int n = n0 + i;
      if (n >= N) break;
      float dvv[V];
      if constexpr (V == 2) {
        float2 t = *(const float2*)(xf + (size_t)n * D + lane * 2);
        dvv[0] = t.x; dvv[1] = t.y;
      } else {
        float4 t = *(const float4*)(xf + (size_t)n * D + lane * 4);
        dvv[0] = t.x; dvv[1] = t.y; dvv[2] = t.z; dvv[3] = t.w;
      }
      float ssq = 0.f;
#pragma unroll
      for (int q = 0; q < V; ++q) ssq += dvv[q] * dvv[q];
      ssq = wave_reduce_sum(ssq);
      bool sp = ssq > 0.5f * fmaxf(ssq, EPS);
      float* arow = agg + (size_t)n * D;
      if constexpr (V == 2) {
        *(float2*)(arow + lane * 2) =
            sp ? make_float2(dvv[0], dvv[1]) : make_float2(0.f, 0.f);
      } else {
        *(float4*)(arow + lane * 4) =
            sp ? make_float4(dvv[0], dvv[1], dvv[2], dvv[3])
               : make_float4(0.f, 0.f, 0.f, 0.f);
      }
    }
  }
  __syncthreads();  // init visible before any atomics; qtile/npd/eoff ready

  const int bstart = eoff[0];
  const int bend = eoff[64];

  for (int base = bstart; base < bend; base += 512) {
    int e0 = base + tid;
    bool valid = e0 < bend;
    int s = valid ? ssrc[e0] : 0;
    float4 nps = valid ? nprop[s] : make_float4(0.f, 0.f, 0.f, 0.f);
    // binary search for local dst: eoff[d] <= e0 < eoff[d+1]
    int lo = 0, hi = 63;
#pragma unroll
    for (int it = 0; it < 6; ++it) {
      int mid = (lo + hi) >> 1;
      if (e0 >= eoff[mid + 1]) lo = mid + 1; else hi = mid;
    }
    const int dloc = lo;
    float4 npdl = npd[dloc];
    const signed char* srow = qt + (size_t)s * D;
    const signed char* drow = qtile + dloc * RB;
    int id = 0;
#pragma unroll
    for (int g = 0; g < NG; ++g) {
      int4 a = *(const int4*)(srow + g * 16);
      int4 bq = *(const int4*)(drow + g * 16);
      id = sdot4i(a.x, bq.x, id);
      id = sdot4i(a.y, bq.y, id);
      id = sdot4i(a.z, bq.z, id);
      id = sdot4i(a.w, bq.w, id);
    }
    float denom = fmaxf(nps.x * npdl.x, EPS);
    float thr = 0.5f * denom;
    float approx = (nps.y * npdl.y) * (float)id;
    float m = 0.5002f * (nps.y * npdl.z + npdl.y * nps.z) + 2e-6f * denom + 1e-7f;
    bool maybe = valid && (approx > thr - m);
    unsigned long long mask = __ballot(maybe);
    // wave-cooperative exact path for each flagged lane's edge
    while (mask) {
      int ln = __ffsll((long long)mask) - 1;
      mask &= mask - 1;
      int es = __shfl(s, ln);
      int dl = __shfl(dloc, ln);
      float nsx = __shfl(nps.x, ln);
      int dn = n0 + dl;
      float sv[V], dvv[V];
      if constexpr (V == 2) {
        float2 a = *(const float2*)(xf + (size_t)es * D + lane * 2);
        float2 b = *(const float2*)(xf + (size_t)dn * D + lane * 2);
        sv[0] = a.x; sv[1] = a.y; dvv[0] = b.x; dvv[1] = b.y;
      } else {
        float4 a = *(const float4*)(xf + (size_t)es * D + lane * 4);
        float4 b = *(const float4*)(xf + (size_t)dn * D + lane * 4);
        sv[0] = a.x; sv[1] = a.y; sv[2] = a.z; sv[3] = a.w;
        dvv[0] = b.x; dvv[1] = b.y; dvv[2] = b.z; dvv[3] = b.w;
      }
      float dx = 0.f;
#pragma unroll
      for (int q = 0; q < V; ++q) dx += sv[q] * dvv[q];
      dx = wave_reduce_sum(dx);
      float ndx = npd[dl].x;
      if (dx > 0.5f * fmaxf(nsx * ndx, EPS)) {
        float* arow = agg + (size_t)dn * D + lane * V;
#pragma unroll
        for (int q = 0; q < V; ++q) atomicAdd(&arow[q], sv[q]);
      }
    }
  }
}

// ---------------- GEMM1: h = relu(A @ W^T + b), 128x128 tile --------------
template <int BM, int BN, int BK, int TM, bool RELU>
__global__ __launch_bounds__(256) void gemm_v2(
    const float* __restrict__ A, const float* __restrict__ W,
    const float* __restrict__ bias, float* __restrict__ C,
    int M, int N, int K) {
  constexpr int NTX = BN / 8;
  constexpr int NTY = 256 / NTX;
  static_assert(BM == NTY * TM, "tile shape");
  constexpr int KQ = BK / 4;
  constexpr int L4A = BM * KQ / 256;
  constexpr int L4B = BN * KQ / 256;
  __shared__ float As[BK][BM];
  __shared__ float Bs[BK][BN];
  const int tid = threadIdx.x;
  const int m0 = blockIdx.x * BM;
  const int n0 = blockIdx.y * BN;
  const int tx = tid % NTX;
  const int ty = tid / NTX;
  const int ms = ty * TM;
  const int ns = tx * 4;
  float acc[TM][8] = {};
  for (int k0 = 0; k0 < K; k0 += BK) {
#pragma unroll
    for (int t = 0; t < L4A; ++t) {
      int f = tid + t * 256;
      int row = f / KQ, kq = f % KQ;
      int gm = m0 + row;
      float4 a = (gm < M) ? *(const float4*)&A[(size_t)gm * K + k0 + kq * 4]
                          : make_float4(0.f, 0.f, 0.f, 0.f);
      As[kq * 4 + 0][row] = a.x; As[kq * 4 + 1][row] = a.y;
      As[kq * 4 + 2][row] = a.z; As[kq * 4 + 3][row] = a.w;
    }
#pragma unroll
    for (int t = 0; t < L4B; ++t) {
      int f = tid + t * 256;
      int row = f / KQ, kq = f % KQ;
      float4 b = *(const float4*)&W[(size_t)(n0 + row) * K + k0 + kq * 4];
      Bs[kq * 4 + 0][row] = b.x; Bs[kq * 4 + 1][row] = b.y;
      Bs[kq * 4 + 2][row] = b.z; Bs[kq * 4 + 3][row] = b.w;
    }
    __syncthreads();
#pragma unroll
    for (int kk = 0; kk < BK; ++kk) {
      float av[TM];
#pragma unroll
      for (int i = 0; i < TM / 4; ++i) {
        float4 t = *(const float4*)&As[kk][ms + i * 4];
        av[i * 4 + 0] = t.x; av[i * 4 + 1] = t.y;
        av[i * 4 + 2] = t.z; av[i * 4 + 3] = t.w;
      }
      float4 b0 = *(const float4*)&Bs[kk][ns];
      float4 b1 = *(const float4*)&Bs[kk][ns + BN / 2];
      float bv[8] = {b0.x, b0.y, b0.z, b0.w, b1.x, b1.y, b1.z, b1.w};
#pragma unroll
      for (int i = 0; i < TM; ++i)
#pragma unroll
        for (int j = 0; j < 8; ++j) acc[i][j] += av[i] * bv[j];
    }
    __syncthreads();
  }
  float4 bb0 = *(const float4*)&bias[n0 + ns];
  float4 bb1 = *(const float4*)&bias[n0 + BN / 2 + ns];
  float bv[8] = {bb0.x, bb0.y, bb0.z, bb0.w, bb1.x, bb1.y, bb1.z, bb1.w};
#pragma unroll
  for (int i = 0; i < TM; ++i) {
    int gm = m0 + ms + i;
    if (gm >= M) continue;
    float t[8];
#pragma unroll
    for (int j = 0; j < 8; ++j) {
      t[j] = acc[i][j] + bv[j];
      if (RELU) t[j] = fmaxf(t[j], 0.f);
    }
#pragma unroll
    for (int grp = 0; grp < 2; ++grp) {
      float4 o = {t[grp * 4 + 0], t[grp * 4 + 1], t[grp * 4 + 2],
                  t[grp * 4 + 3]};
      *(float4*)&C[(size_t)gm * N + n0 + grp * (BN / 2) + ns] = o;
    }
  }
}

// ------- GEMM2 fused with log_softmax: out = lsm(A @ W^T + b), BN=64 ------
__global__ __launch_bounds__(256) void gemm2_lsm(
    const float* __restrict__ A, const float* __restrict__ W,
    const float* __restrict__ bias, float* __restrict__ out, int M, int K) {
  constexpr int BM = 128, BN = 64, BK = 32, TM = 4;
  constexpr int NTX = BN / 8;     // 8
  constexpr int KQ = BK / 4;      // 8
  constexpr int L4A = BM * KQ / 256;  // 4
  constexpr int L4B = BN * KQ / 256;  // 2
  __shared__ float smem[BM * 65];
  float* As = smem;                   // [BK][BM]
  float* Bs = smem + BK * BM;         // [BK][BN]
  const int tid = threadIdx.x;
  const int m0 = blockIdx.x * BM;
  const int tx = tid % NTX;
  const int ty = tid / NTX;
  const int ms = ty * TM;
  const int ns = tx * 4;
  float acc[TM][8] = {};
  for (int k0 = 0; k0 < K; k0 += BK) {
#pragma unroll
    for (int t = 0; t < L4A; ++t) {
      int f = tid + t * 256;
      int row = f / KQ, kq = f % KQ;
      int gm = m0 + row;
      float4 a = (gm < M) ? *(const float4*)&A[(size_t)gm * K + k0 + kq * 4]
                          : make_float4(0.f, 0.f, 0.f, 0.f);
      As[(kq * 4 + 0) * BM + row] = a.x; As[(kq * 4 + 1) * BM + row] = a.y;
      As[(kq * 4 + 2) * BM + row] = a.z; As[(kq * 4 + 3) * BM + row] = a.w;
    }
#pragma unroll
    for (int t = 0; t < L4B; ++t) {
      int f = tid + t * 256;
      int row = f / KQ, kq = f % KQ;
      float4 b = *(const float4*)&W[(size_t)row * K + k0 + kq * 4];
      Bs[(kq * 4 + 0) * BN + row] = b.x; Bs[(kq * 4 + 1) * BN + row] = b.y;
      Bs[(kq * 4 + 2) * BN + row] = b.z; Bs[(kq * 4 + 3) * BN + row] = b.w;
    }
    __syncthreads();
#pragma unroll
    for (int kk = 0; kk < BK; ++kk) {
      float4 a4 = *(const float4*)&As[kk * BM + ms];
      float av[4] = {a4.x, a4.y, a4.z, a4.w};
      float4 b0 = *(const float4*)&Bs[kk * BN + ns];
      float4 b1 = *(const float4*)&Bs[kk * BN + ns + 32];
      float bv[8] = {b0.x, b0.y, b0.z, b0.w, b1.x, b1.y, b1.z, b1.w};
#pragma unroll
      for (int i = 0; i < TM; ++i)
#pragma unroll
        for (int j = 0; j < 8; ++j) acc[i][j] += av[i] * bv[j];
    }
    __syncthreads();
  }
  float4 bb0 = *(const float4*)&bias[ns];
  float4 bb1 = *(const float4*)&bias[32 + ns];
  float bv[8] = {bb0.x, bb0.y, bb0.z, bb0.w, bb1.x, bb1.y, bb1.z, bb1.w};
#pragma unroll
  for (int i = 0; i < TM; ++i) {
    int row = ms + i;
#pragma unroll
    for (int grp = 0; grp < 2; ++grp)
#pragma unroll
      for (int j = 0; j < 4; ++j)
        smem[row * 65 + grp * 32 + ns + j] = acc[i][grp * 4 + j] + bv[grp * 4 + j];
  }
  __syncthreads();
  int w = tid >> 6, lane = tid & 63;
  for (int r = w; r < BM; r += 4) {
    int gm = m0 + r;
    if (gm >= M) continue;
    float v = smem[r * 65 + lane];
    float mx = wave_reduce_max(v);
    float e = expf(v - mx);
    float sm = wave_reduce_sum(e);
    out[(size_t)gm * 64 + lane] = v - mx - logf(sm);
  }
}

extern "C" void kernel_launch(void* const* d_in, const int* in_sizes, int n_in,
                              void* d_out, int out_size, void* d_ws,
                              size_t ws_size, hipStream_t stream) {
  const float* x  = (const float*)d_in[0];
  const int* eidx = (const int*)d_in[1];
  const float* W1 = (const float*)d_in[2];
  const float* b1 = (const float*)d_in[3];
  const float* W2 = (const float*)d_in[4];
  const float* b2 = (const float*)d_in[5];
  float* out = (float*)d_out;

  const int N = in_sizes[0] / 128;  // 50000
  const int E = in_sizes[1] / 2;    // 800000
  const int* src = eidx;
  const int* dst = eidx + E;

  const int nbuck = (N + 63) / 64;         // 782
  const int ntot = nbuck * NB_SORT;        // 200192
  const int nblk2 = (ntot + 1023) / 1024;  // 196

  float* agg    = (float*)d_ws;
  float* h      = agg + (size_t)N * 256;
  float4* npx   = (float4*)(h + (size_t)N * 256);
  float4* nph   = npx + N;
  int* S        = (int*)(nph + N);
  int* bsum     = S + ntot;
  int* ssrc     = bsum + 256;
  int* endoff   = ssrc + E;
  signed char* qh = (signed char*)(endoff + N);
  int2* epair   = (int2*)h;                              // overlap (6.4 MB)
  signed char* qx = (signed char*)(h + (size_t)N * 64);  // overlap (6.4 MB)

  // ---- build CSR (by dst) with LDS-only atomics ----
  hist_coarse<<<NB_SORT, 256, 0, stream>>>(dst, S, E, nbuck);
  scan_local<<<nblk2, 256, 0, stream>>>(S, bsum, ntot);
  scan_bsum<<<1, 256, 0, stream>>>(bsum, nblk2);
  add_bsum<<<(ntot + 255) / 256, 256, 0, stream>>>(S, bsum, ntot);
  scatter_coarse<<<NB_SORT, 256, 0, stream>>>(src, dst, S, epair, E, nbuck);
  fine_sort<<<nbuck, 256, 0, stream>>>(epair, S, ssrc, endoff, E, nbuck, N);

  // ---- layer 1 (D=128) ----
  prep_x<<<(N + 3) / 4, 256, 0, stream>>>(x, qx, npx, N);
  conv_lpe<128><<<nbuck, 512, 0, stream>>>(x, qx, npx, ssrc, endoff, agg, N);
  gemm_v2<128, 128, 32, 8, true>
      <<<dim3((N + 127) / 128, 2), 256, 0, stream>>>(agg, W1, b1, h, N, 256,
                                                     128);

  // ---- layer 2 (D=256) ----
  prep_h<<<(N + 3) / 4, 256, 0, stream>>>(h, qh, nph, N);
  conv_lpe<256><<<nbuck, 512, 0, stream>>>(h, qh, nph, ssrc, endoff, agg, N);
  gemm2_lsm<<<dim3((N + 127) / 128), 256, 0, stream>>>(agg, W2, b2, out, N,
                                                       256);
}

// Round 12
// 343.500 us; speedup vs baseline: 1.0636x; 1.0636x over previous
//
#include <hip/hip_runtime.h>
#include <math.h>

#define EPS 1e-8f
#define NB_SORT 256  // blocks in coarse sort phases

#if defined(__has_builtin)
#if __has_builtin(__builtin_amdgcn_sdot4)
#define HAVE_SDOT4 1
#endif
#endif

__device__ __forceinline__ int sdot4i(int a, int b, int c) {
#ifdef HAVE_SDOT4
  return __builtin_amdgcn_sdot4(a, b, c, false);
#else
  return c + ((int)(signed char)(a)) * ((int)(signed char)(b)) +
         ((int)(signed char)(a >> 8)) * ((int)(signed char)(b >> 8)) +
         ((int)(signed char)(a >> 16)) * ((int)(signed char)(b >> 16)) +
         (a >> 24) * (b >> 24);
#endif
}

__device__ __forceinline__ float wave_reduce_sum(float v) {
#pragma unroll
  for (int off = 32; off > 0; off >>= 1)
    v += __shfl_xor(v, off, 64);
  return v;
}

__device__ __forceinline__ float wave_reduce_max(float v) {
#pragma unroll
  for (int off = 32; off > 0; off >>= 1)
    v = fmaxf(v, __shfl_xor(v, off, 64));
  return v;
}

__device__ __forceinline__ float dot4(float4 a, float4 b) {
  return a.x * b.x + a.y * b.y + a.z * b.z + a.w * b.w;
}

__device__ __forceinline__ int clampq(float q) {
  int i = (int)rintf(q);
  return i < -127 ? -127 : (i > 127 ? 127 : i);
}

// ============ CSR build: 2-level bucket sort, LDS atomics only ============
__global__ __launch_bounds__(256) void hist_coarse(const int* __restrict__ dst,
                                                   int* __restrict__ hist_blk,
                                                   int E, int nbuck) {
  __shared__ int lh[1024];
  int t = threadIdx.x, blk = blockIdx.x;
  for (int i = t; i < nbuck; i += 256) lh[i] = 0;
  __syncthreads();
  int ch = (E + NB_SORT - 1) / NB_SORT;
  int lo = blk * ch, hi = min(E, lo + ch);
  for (int e = lo + t; e < hi; e += 256) atomicAdd(&lh[dst[e] >> 6], 1);
  __syncthreads();
  for (int i = t; i < nbuck; i += 256) hist_blk[i * NB_SORT + blk] = lh[i];
}

__global__ __launch_bounds__(256) void scan_local(int* __restrict__ hist,
                                                  int* __restrict__ bsum,
                                                  int nb) {
  __shared__ int tsum[256];
  int t = threadIdx.x;
  int base = blockIdx.x * 1024 + t * 4;
  int v0 = 0, v1 = 0, v2 = 0, v3 = 0;
  if (base + 3 < nb) {
    int4 q = *(const int4*)&hist[base];
    v0 = q.x; v1 = q.y; v2 = q.z; v3 = q.w;
  } else {
    if (base + 0 < nb) v0 = hist[base + 0];
    if (base + 1 < nb) v1 = hist[base + 1];
    if (base + 2 < nb) v2 = hist[base + 2];
  }
  tsum[t] = v0 + v1 + v2 + v3;
  __syncthreads();
  for (int off = 1; off < 256; off <<= 1) {
    int u = 0;
    if (t >= off) u = tsum[t - off];
    __syncthreads();
    if (t >= off) tsum[t] += u;
    __syncthreads();
  }
  int excl = (t == 0) ? 0 : tsum[t - 1];
  int e0 = excl, e1 = excl + v0, e2 = e1 + v1, e3 = e2 + v2;
  if (base + 3 < nb) {
    *(int4*)&hist[base] = make_int4(e0, e1, e2, e3);
  } else {
    if (base + 0 < nb) hist[base + 0] = e0;
    if (base + 1 < nb) hist[base + 1] = e1;
    if (base + 2 < nb) hist[base + 2] = e2;
  }
  if (t == 255) bsum[blockIdx.x] = tsum[255];
}

__global__ __launch_bounds__(256) void scan_bsum(int* __restrict__ bsum,
                                                 int nblk) {
  __shared__ int sh[256];
  int t = threadIdx.x;
  sh[t] = (t < nblk) ? bsum[t] : 0;
  __syncthreads();
  for (int off = 1; off < 256; off <<= 1) {
    int u = 0;
    if (t >= off) u = sh[t - off];
    __syncthreads();
    if (t >= off) sh[t] += u;
    __syncthreads();
  }
  if (t < nblk) bsum[t] = (t == 0) ? 0 : sh[t - 1];
}

__global__ __launch_bounds__(256) void add_bsum(int* __restrict__ hist,
                                                const int* __restrict__ bsum,
                                                int nb) {
  int i = blockIdx.x * blockDim.x + threadIdx.x;
  if (i < nb) hist[i] += bsum[i >> 10];
}

__global__ __launch_bounds__(256) void scatter_coarse(
    const int* __restrict__ src, const int* __restrict__ dst,
    const int* __restrict__ S, int2* __restrict__ epair, int E, int nbuck) {
  __shared__ int lb[1024];
  int t = threadIdx.x, blk = blockIdx.x;
  for (int i = t; i < nbuck; i += 256) lb[i] = S[i * NB_SORT + blk];
  __syncthreads();
  int ch = (E + NB_SORT - 1) / NB_SORT;
  int lo = blk * ch, hi = min(E, lo + ch);
  for (int e = lo + t; e < hi; e += 256) {
    int d = dst[e];
    int pos = atomicAdd(&lb[d >> 6], 1);
    epair[pos] = make_int2(src[e], d);
  }
}

__global__ __launch_bounds__(256) void fine_sort(
    const int2* __restrict__ epair, const int* __restrict__ S,
    int* __restrict__ ssrc, int* __restrict__ endoff, int E, int nbuck,
    int N) {
  __shared__ int fh[64];
  __shared__ int cur[64];
  int b = blockIdx.x, t = threadIdx.x;
  int bstart = S[b * NB_SORT];
  int bend = (b + 1 < nbuck) ? S[(b + 1) * NB_SORT] : E;
  if (t < 64) fh[t] = 0;
  __syncthreads();
  for (int e = bstart + t; e < bend; e += 256)
    atomicAdd(&fh[epair[e].y & 63], 1);
  __syncthreads();
  if (t < 64) {
    int v = fh[t];
    int incl = v;
#pragma unroll
    for (int off = 1; off < 64; off <<= 1) {
      int u = __shfl_up(incl, off, 64);
      if (t >= off) incl += u;
    }
    cur[t] = incl - v;
    int d = b * 64 + t;
    if (d < N) endoff[d] = bstart + incl;
  }
  __syncthreads();
  for (int e = bstart + t; e < bend; e += 256) {
    int2 p = epair[e];
    int pos = atomicAdd(&cur[p.y & 63], 1);
    ssrc[bstart + pos] = p.x;
  }
}

// ============ prep: quantize + node props + self-loop agg init ============
// nprop = (norm2, scale, L1m, 0); quantization error per edge (s,d) bounded:
// |dot - s_s*s_d*idot| <= 0.5002*(s_s*L1m_d + s_d*L1m_s).
// Also writes agg init = selfpass ? row : 0 (hoisted out of conv: the row and
// ssq are already in registers here; conv then does pure edge work + atomics,
// ordering guaranteed by kernel boundary).
__global__ __launch_bounds__(256) void prep_x(const float* __restrict__ x,
                                              signed char* __restrict__ qx,
                                              float4* __restrict__ nprop,
                                              float* __restrict__ agg,
                                              int N) {
  int node = (int)((blockIdx.x * blockDim.x + threadIdx.x) >> 6);
  int lane = threadIdx.x & 63;
  if (node >= N) return;
  float2 v = *(const float2*)(x + (size_t)node * 128 + lane * 2);
  float ax = fabsf(v.x), ay = fabsf(v.y);
  float mx = wave_reduce_max(fmaxf(ax, ay));
  float l1 = wave_reduce_sum(ax + ay);
  float ss = wave_reduce_sum(v.x * v.x + v.y * v.y);
  float s = mx * (1.0f / 127.0f);
  float inv = (mx > 0.f) ? 127.0f / mx : 0.f;
  int q0 = clampq(v.x * inv), q1 = clampq(v.y * inv);
  unsigned short w = (unsigned short)((q0 & 0xff) | ((q1 & 0xff) << 8));
  ((unsigned short*)(qx + (size_t)node * 128))[lane] = w;
  float l1q = s * wave_reduce_sum((float)(abs(q0) + abs(q1)));
  bool sp = ss > 0.5f * fmaxf(ss, EPS);
  *(float2*)(agg + (size_t)node * 128 + lane * 2) =
      sp ? v : make_float2(0.f, 0.f);
  if (lane == 0)
    nprop[node] = make_float4(sqrtf(ss), s, fmaxf(l1, l1q), 0.f);
}

__global__ __launch_bounds__(256) void prep_h(const float* __restrict__ h,
                                              signed char* __restrict__ qh,
                                              float4* __restrict__ nprop,
                                              float* __restrict__ agg,
                                              int N) {
  int node = (int)((blockIdx.x * blockDim.x + threadIdx.x) >> 6);
  int lane = threadIdx.x & 63;
  if (node >= N) return;
  float4 v = *(const float4*)(h + (size_t)node * 256 + lane * 4);
  float ax = fabsf(v.x), ay = fabsf(v.y), az = fabsf(v.z), aw = fabsf(v.w);
  float mx = wave_reduce_max(fmaxf(fmaxf(ax, ay), fmaxf(az, aw)));
  float l1 = wave_reduce_sum(ax + ay + az + aw);
  float ss = wave_reduce_sum(dot4(v, v));
  float s = mx * (1.0f / 127.0f);
  float inv = (mx > 0.f) ? 127.0f / mx : 0.f;
  int q0 = clampq(v.x * inv), q1 = clampq(v.y * inv);
  int q2 = clampq(v.z * inv), q3 = clampq(v.w * inv);
  int w = (q0 & 0xff) | ((q1 & 0xff) << 8) | ((q2 & 0xff) << 16) | (q3 << 24);
  ((int*)(qh + (size_t)node * 256))[lane] = w;
  float l1q = s * wave_reduce_sum((float)(abs(q0) + abs(q1) + abs(q2) + abs(q3)));
  bool sp = ss > 0.5f * fmaxf(ss, EPS);
  *(float4*)(agg + (size_t)node * 256 + lane * 4) =
      sp ? v : make_float4(0.f, 0.f, 0.f, 0.f);
  if (lane == 0)
    nprop[node] = make_float4(sqrtf(ss), s, fmaxf(l1, l1q), 0.f);
}

// ====== conv, lane-per-edge: one 512-thread block per 64-node bucket ======
// Pure edge phase (self-loop init hoisted to prep): lane-per-edge int8 screen
// against the LDS dst tile, no cross-lane reduce; rare screen-passers handled
// wave-cooperatively (ballot -> exact fp32 gather + wave reduce + atomicAdd).
template <int D>
__global__ __launch_bounds__(512) void conv_lpe(
    const float* __restrict__ xf, const signed char* __restrict__ qt,
    const float4* __restrict__ nprop, const int* __restrict__ ssrc,
    const int* __restrict__ endoff, float* __restrict__ agg, int N) {
  constexpr int RB = D + 16;  // padded LDS row bytes
  constexpr int NG = D / 16;  // int4 chunks per row
  constexpr int V = D / 64;   // fp32 elems per lane (exact path)
  __shared__ signed char qtile[64 * RB];
  __shared__ float4 npd[64];
  __shared__ int eoff[65];
  const int tid = threadIdx.x;
  const int lane = tid & 63;
  const int n0 = blockIdx.x * 64;

  if (tid < 65) {
    int idx = n0 - 1 + tid;
    eoff[tid] = (idx < 0) ? 0 : endoff[min(idx, N - 1)];
  }
  if (tid >= 64 && tid < 128) {
    int i = tid - 64;
    int n = n0 + i;
    npd[i] = (n < N) ? nprop[n] : make_float4(0.f, 0.f, 0.f, 0.f);
  }
  for (int j = tid; j < 64 * NG; j += 512) {
    int r = j / NG, c = j % NG;
    int n = n0 + r;
    int4 v = (n < N) ? *(const int4*)(qt + (size_t)n * D + c * 16)
                     : make_int4(0, 0, 0, 0);
    *(int4*)(qtile + r * RB + c * 16) = v;
  }
  __syncthreads();  // qtile/npd/eoff ready

  const int bstart = eoff[0];
  const int bend = eoff[64];

  for (int base = bstart; base < bend; base += 512) {
    int e0 = base + tid;
    bool valid = e0 < bend;
    int s = valid ? ssrc[e0] : 0;
    float4 nps = valid ? nprop[s] : make_float4(0.f, 0.f, 0.f, 0.f);
    // binary search for local dst: eoff[d] <= e0 < eoff[d+1]
    int lo = 0, hi = 63;
#pragma unroll
    for (int it = 0; it < 6; ++it) {
      int mid = (lo + hi) >> 1;
      if (e0 >= eoff[mid + 1]) lo = mid + 1; else hi = mid;
    }
    const int dloc = lo;
    float4 npdl = npd[dloc];
    const signed char* srow = qt + (size_t)s * D;
    const signed char* drow = qtile + dloc * RB;
    int id = 0;
#pragma unroll
    for (int g = 0; g < NG; ++g) {
      int4 a = *(const int4*)(srow + g * 16);
      int4 bq = *(const int4*)(drow + g * 16);
      id = sdot4i(a.x, bq.x, id);
      id = sdot4i(a.y, bq.y, id);
      id = sdot4i(a.z, bq.z, id);
      id = sdot4i(a.w, bq.w, id);
    }
    float denom = fmaxf(nps.x * npdl.x, EPS);
    float thr = 0.5f * denom;
    float approx = (nps.y * npdl.y) * (float)id;
    float m = 0.5002f * (nps.y * npdl.z + npdl.y * nps.z) + 2e-6f * denom + 1e-7f;
    bool maybe = valid && (approx > thr - m);
    unsigned long long mask = __ballot(maybe);
    // wave-cooperative exact path for each flagged lane's edge
    while (mask) {
      int ln = __ffsll((long long)mask) - 1;
      mask &= mask - 1;
      int es = __shfl(s, ln);
      int dl = __shfl(dloc, ln);
      float nsx = __shfl(nps.x, ln);
      int dn = n0 + dl;
      float sv[V], dvv[V];
      if constexpr (V == 2) {
        float2 a = *(const float2*)(xf + (size_t)es * D + lane * 2);
        float2 b = *(const float2*)(xf + (size_t)dn * D + lane * 2);
        sv[0] = a.x; sv[1] = a.y; dvv[0] = b.x; dvv[1] = b.y;
      } else {
        float4 a = *(const float4*)(xf + (size_t)es * D + lane * 4);
        float4 b = *(const float4*)(xf + (size_t)dn * D + lane * 4);
        sv[0] = a.x; sv[1] = a.y; sv[2] = a.z; sv[3] = a.w;
        dvv[0] = b.x; dvv[1] = b.y; dvv[2] = b.z; dvv[3] = b.w;
      }
      float dx = 0.f;
#pragma unroll
      for (int q = 0; q < V; ++q) dx += sv[q] * dvv[q];
      dx = wave_reduce_sum(dx);
      float ndx = npd[dl].x;
      if (dx > 0.5f * fmaxf(nsx * ndx, EPS)) {
        float* arow = agg + (size_t)dn * D + lane * V;
#pragma unroll
        for (int q = 0; q < V; ++q) atomicAdd(&arow[q], sv[q]);
      }
    }
  }
}

// ---------------- GEMM1: h = relu(A @ W^T + b), 128x128 tile --------------
template <int BM, int BN, int BK, int TM, bool RELU>
__global__ __launch_bounds__(256) void gemm_v2(
    const float* __restrict__ A, const float* __restrict__ W,
    const float* __restrict__ bias, float* __restrict__ C,
    int M, int N, int K) {
  constexpr int NTX = BN / 8;
  constexpr int NTY = 256 / NTX;
  static_assert(BM == NTY * TM, "tile shape");
  constexpr int KQ = BK / 4;
  constexpr int L4A = BM * KQ / 256;
  constexpr int L4B = BN * KQ / 256;
  __shared__ float As[BK][BM];
  __shared__ float Bs[BK][BN];
  const int tid = threadIdx.x;
  const int m0 = blockIdx.x * BM;
  const int n0 = blockIdx.y * BN;
  const int tx = tid % NTX;
  const int ty = tid / NTX;
  const int ms = ty * TM;
  const int ns = tx * 4;
  float acc[TM][8] = {};
  for (int k0 = 0; k0 < K; k0 += BK) {
#pragma unroll
    for (int t = 0; t < L4A; ++t) {
      int f = tid + t * 256;
      int row = f / KQ, kq = f % KQ;
      int gm = m0 + row;
      float4 a = (gm < M) ? *(const float4*)&A[(size_t)gm * K + k0 + kq * 4]
                          : make_float4(0.f, 0.f, 0.f, 0.f);
      As[kq * 4 + 0][row] = a.x; As[kq * 4 + 1][row] = a.y;
      As[kq * 4 + 2][row] = a.z; As[kq * 4 + 3][row] = a.w;
    }
#pragma unroll
    for (int t = 0; t < L4B; ++t) {
      int f = tid + t * 256;
      int row = f / KQ, kq = f % KQ;
      float4 b = *(const float4*)&W[(size_t)(n0 + row) * K + k0 + kq * 4];
      Bs[kq * 4 + 0][row] = b.x; Bs[kq * 4 + 1][row] = b.y;
      Bs[kq * 4 + 2][row] = b.z; Bs[kq * 4 + 3][row] = b.w;
    }
    __syncthreads();
#pragma unroll
    for (int kk = 0; kk < BK; ++kk) {
      float av[TM];
#pragma unroll
      for (int i = 0; i < TM / 4; ++i) {
        float4 t = *(const float4*)&As[kk][ms + i * 4];
        av[i * 4 + 0] = t.x; av[i * 4 + 1] = t.y;
        av[i * 4 + 2] = t.z; av[i * 4 + 3] = t.w;
      }
      float4 b0 = *(const float4*)&Bs[kk][ns];
      float4 b1 = *(const float4*)&Bs[kk][ns + BN / 2];
      float bv[8] = {b0.x, b0.y, b0.z, b0.w, b1.x, b1.y, b1.z, b1.w};
#pragma unroll
      for (int i = 0; i < TM; ++i)
#pragma unroll
        for (int j = 0; j < 8; ++j) acc[i][j] += av[i] * bv[j];
    }
    __syncthreads();
  }
  float4 bb0 = *(const float4*)&bias[n0 + ns];
  float4 bb1 = *(const float4*)&bias[n0 + BN / 2 + ns];
  float bv[8] = {bb0.x, bb0.y, bb0.z, bb0.w, bb1.x, bb1.y, bb1.z, bb1.w};
#pragma unroll
  for (int i = 0; i < TM; ++i) {
    int gm = m0 + ms + i;
    if (gm >= M) continue;
    float t[8];
#pragma unroll
    for (int j = 0; j < 8; ++j) {
      t[j] = acc[i][j] + bv[j];
      if (RELU) t[j] = fmaxf(t[j], 0.f);
    }
#pragma unroll
    for (int grp = 0; grp < 2; ++grp) {
      float4 o = {t[grp * 4 + 0], t[grp * 4 + 1], t[grp * 4 + 2],
                  t[grp * 4 + 3]};
      *(float4*)&C[(size_t)gm * N + n0 + grp * (BN / 2) + ns] = o;
    }
  }
}

// ------- GEMM2 fused with log_softmax: out = lsm(A @ W^T + b), BN=64 ------
__global__ __launch_bounds__(256) void gemm2_lsm(
    const float* __restrict__ A, const float* __restrict__ W,
    const float* __restrict__ bias, float* __restrict__ out, int M, int K) {
  constexpr int BM = 128, BN = 64, BK = 32, TM = 4;
  constexpr int NTX = BN / 8;     // 8
  constexpr int KQ = BK / 4;      // 8
  constexpr int L4A = BM * KQ / 256;  // 4
  constexpr int L4B = BN * KQ / 256;  // 2
  __shared__ float smem[BM * 65];
  float* As = smem;                   // [BK][BM]
  float* Bs = smem + BK * BM;         // [BK][BN]
  const int tid = threadIdx.x;
  const int m0 = blockIdx.x * BM;
  const int tx = tid % NTX;
  const int ty = tid / NTX;
  const int ms = ty * TM;
  const int ns = tx * 4;
  float acc[TM][8] = {};
  for (int k0 = 0; k0 < K; k0 += BK) {
#pragma unroll
    for (int t = 0; t < L4A; ++t) {
      int f = tid + t * 256;
      int row = f / KQ, kq = f % KQ;
      int gm = m0 + row;
      float4 a = (gm < M) ? *(const float4*)&A[(size_t)gm * K + k0 + kq * 4]
                          : make_float4(0.f, 0.f, 0.f, 0.f);
      As[(kq * 4 + 0) * BM + row] = a.x; As[(kq * 4 + 1) * BM + row] = a.y;
      As[(kq * 4 + 2) * BM + row] = a.z; As[(kq * 4 + 3) * BM + row] = a.w;
    }
#pragma unroll
    for (int t = 0; t < L4B; ++t) {
      int f = tid + t * 256;
      int row = f / KQ, kq = f % KQ;
      float4 b = *(const float4*)&W[(size_t)row * K + k0 + kq * 4];
      Bs[(kq * 4 + 0) * BN + row] = b.x; Bs[(kq * 4 + 1) * BN + row] = b.y;
      Bs[(kq * 4 + 2) * BN + row] = b.z; Bs[(kq * 4 + 3) * BN + row] = b.w;
    }
    __syncthreads();
#pragma unroll
    for (int kk = 0; kk < BK; ++kk) {
      float4 a4 = *(const float4*)&As[kk * BM + ms];
      float av[4] = {a4.x, a4.y, a4.z, a4.w};
      float4 b0 = *(const float4*)&Bs[kk * BN + ns];
      float4 b1 = *(const float4*)&Bs[kk * BN + ns + 32];
      float bv[8] = {b0.x, b0.y, b0.z, b0.w, b1.x, b1.y, b1.z, b1.w};
#pragma unroll
      for (int i = 0; i < TM; ++i)
#pragma unroll
        for (int j = 0; j < 8; ++j) acc[i][j] += av[i] * bv[j];
    }
    __syncthreads();
  }
  float4 bb0 = *(const float4*)&bias[ns];
  float4 bb1 = *(const float4*)&bias[32 + ns];
  float bv[8] = {bb0.x, bb0.y, bb0.z, bb0.w, bb1.x, bb1.y, bb1.z, bb1.w};
#pragma unroll
  for (int i = 0; i < TM; ++i) {
    int row = ms + i;
#pragma unroll
    for (int grp = 0; grp < 2; ++grp)
#pragma unroll
      for (int j = 0; j < 4; ++j)
        smem[row * 65 + grp * 32 + ns + j] = acc[i][grp * 4 + j] + bv[grp * 4 + j];
  }
  __syncthreads();
  int w = tid >> 6, lane = tid & 63;
  for (int r = w; r < BM; r += 4) {
    int gm = m0 + r;
    if (gm >= M) continue;
    float v = smem[r * 65 + lane];
    float mx = wave_reduce_max(v);
    float e = expf(v - mx);
    float sm = wave_reduce_sum(e);
    out[(size_t)gm * 64 + lane] = v - mx - logf(sm);
  }
}

extern "C" void kernel_launch(void* const* d_in, const int* in_sizes, int n_in,
                              void* d_out, int out_size, void* d_ws,
                              size_t ws_size, hipStream_t stream) {
  const float* x  = (const float*)d_in[0];
  const int* eidx = (const int*)d_in[1];
  const float* W1 = (const float*)d_in[2];
  const float* b1 = (const float*)d_in[3];
  const float* W2 = (const float*)d_in[4];
  const float* b2 = (const float*)d_in[5];
  float* out = (float*)d_out;

  const int N = in_sizes[0] / 128;  // 50000
  const int E = in_sizes[1] / 2;    // 800000
  const int* src = eidx;
  const int* dst = eidx + E;

  const int nbuck = (N + 63) / 64;         // 782
  const int ntot = nbuck * NB_SORT;        // 200192
  const int nblk2 = (ntot + 1023) / 1024;  // 196

  float* agg    = (float*)d_ws;
  float* h      = agg + (size_t)N * 256;
  float4* npx   = (float4*)(h + (size_t)N * 256);
  float4* nph   = npx + N;
  int* S        = (int*)(nph + N);
  int* bsum     = S + ntot;
  int* ssrc     = bsum + 256;
  int* endoff   = ssrc + E;
  signed char* qh = (signed char*)(endoff + N);
  int2* epair   = (int2*)h;                              // overlap (6.4 MB)
  signed char* qx = (signed char*)(h + (size_t)N * 64);  // overlap (6.4 MB)

  // ---- build CSR (by dst) with LDS-only atomics ----
  hist_coarse<<<NB_SORT, 256, 0, stream>>>(dst, S, E, nbuck);
  scan_local<<<nblk2, 256, 0, stream>>>(S, bsum, ntot);
  scan_bsum<<<1, 256, 0, stream>>>(bsum, nblk2);
  add_bsum<<<(ntot + 255) / 256, 256, 0, stream>>>(S, bsum, ntot);
  scatter_coarse<<<NB_SORT, 256, 0, stream>>>(src, dst, S, epair, E, nbuck);
  fine_sort<<<nbuck, 256, 0, stream>>>(epair, S, ssrc, endoff, E, nbuck, N);

  // ---- layer 1 (D=128) ----
  prep_x<<<(N + 3) / 4, 256, 0, stream>>>(x, qx, npx, agg, N);
  conv_lpe<128><<<nbuck, 512, 0, stream>>>(x, qx, npx, ssrc, endoff, agg, N);
  gemm_v2<128, 128, 32, 8, true>
      <<<dim3((N + 127) / 128, 2), 256, 0, stream>>>(agg, W1, b1, h, N, 256,
                                                     128);

  // ---- layer 2 (D=256) ----
  prep_h<<<(N + 3) / 4, 256, 0, stream>>>(h, qh, nph, agg, N);
  conv_lpe<256><<<nbuck, 512, 0, stream>>>(h, qh, nph, ssrc, endoff, agg, N);
  gemm2_lsm<<<dim3((N + 127) / 128), 256, 0, stream>>>(agg, W2, b2, out, N,
                                                       256);
}

// Round 13
// 331.530 us; speedup vs baseline: 1.1020x; 1.0361x over previous
//
#include <hip/hip_runtime.h>
#include <math.h>

#define EPS 1e-8f
#define NB_SORT 256  // blocks in coarse sort phases

#if defined(__has_builtin)
#if __has_builtin(__builtin_amdgcn_sdot4)
#define HAVE_SDOT4 1
#endif
#endif

__device__ __forceinline__ int sdot4i(int a, int b, int c) {
#ifdef HAVE_SDOT4
  return __builtin_amdgcn_sdot4(a, b, c, false);
#else
  return c + ((int)(signed char)(a)) * ((int)(signed char)(b)) +
         ((int)(signed char)(a >> 8)) * ((int)(signed char)(b >> 8)) +
         ((int)(signed char)(a >> 16)) * ((int)(signed char)(b >> 16)) +
         (a >> 24) * (b >> 24);
#endif
}

__device__ __forceinline__ float wave_reduce_sum(float v) {
#pragma unroll
  for (int off = 32; off > 0; off >>= 1)
    v += __shfl_xor(v, off, 64);
  return v;
}

__device__ __forceinline__ float wave_reduce_max(float v) {
#pragma unroll
  for (int off = 32; off > 0; off >>= 1)
    v = fmaxf(v, __shfl_xor(v, off, 64));
  return v;
}

__device__ __forceinline__ float dot4(float4 a, float4 b) {
  return a.x * b.x + a.y * b.y + a.z * b.z + a.w * b.w;
}

__device__ __forceinline__ int clampq(float q) {
  int i = (int)rintf(q);
  return i < -127 ? -127 : (i > 127 ? 127 : i);
}

// ============ CSR build: 2-level bucket sort, LDS atomics only ============
__global__ __launch_bounds__(256) void hist_coarse(const int* __restrict__ dst,
                                                   int* __restrict__ hist_blk,
                                                   int E, int nbuck) {
  __shared__ int lh[1024];
  int t = threadIdx.x, blk = blockIdx.x;
  for (int i = t; i < nbuck; i += 256) lh[i] = 0;
  __syncthreads();
  int ch = (E + NB_SORT - 1) / NB_SORT;
  int lo = blk * ch, hi = min(E, lo + ch);
  for (int e = lo + t; e < hi; e += 256) atomicAdd(&lh[dst[e] >> 6], 1);
  __syncthreads();
  for (int i = t; i < nbuck; i += 256) hist_blk[i * NB_SORT + blk] = lh[i];
}

__global__ __launch_bounds__(256) void scan_local(int* __restrict__ hist,
                                                  int* __restrict__ bsum,
                                                  int nb) {
  __shared__ int tsum[256];
  int t = threadIdx.x;
  int base = blockIdx.x * 1024 + t * 4;
  int v0 = 0, v1 = 0, v2 = 0, v3 = 0;
  if (base + 3 < nb) {
    int4 q = *(const int4*)&hist[base];
    v0 = q.x; v1 = q.y; v2 = q.z; v3 = q.w;
  } else {
    if (base + 0 < nb) v0 = hist[base + 0];
    if (base + 1 < nb) v1 = hist[base + 1];
    if (base + 2 < nb) v2 = hist[base + 2];
  }
  tsum[t] = v0 + v1 + v2 + v3;
  __syncthreads();
  for (int off = 1; off < 256; off <<= 1) {
    int u = 0;
    if (t >= off) u = tsum[t - off];
    __syncthreads();
    if (t >= off) tsum[t] += u;
    __syncthreads();
  }
  int excl = (t == 0) ? 0 : tsum[t - 1];
  int e0 = excl, e1 = excl + v0, e2 = e1 + v1, e3 = e2 + v2;
  if (base + 3 < nb) {
    *(int4*)&hist[base] = make_int4(e0, e1, e2, e3);
  } else {
    if (base + 0 < nb) hist[base + 0] = e0;
    if (base + 1 < nb) hist[base + 1] = e1;
    if (base + 2 < nb) hist[base + 2] = e2;
  }
  if (t == 255) bsum[blockIdx.x] = tsum[255];
}

__global__ __launch_bounds__(256) void scan_bsum(int* __restrict__ bsum,
                                                 int nblk) {
  __shared__ int sh[256];
  int t = threadIdx.x;
  sh[t] = (t < nblk) ? bsum[t] : 0;
  __syncthreads();
  for (int off = 1; off < 256; off <<= 1) {
    int u = 0;
    if (t >= off) u = sh[t - off];
    __syncthreads();
    if (t >= off) sh[t] += u;
    __syncthreads();
  }
  if (t < nblk) bsum[t] = (t == 0) ? 0 : sh[t - 1];
}

__global__ __launch_bounds__(256) void add_bsum(int* __restrict__ hist,
                                                const int* __restrict__ bsum,
                                                int nb) {
  int i = blockIdx.x * blockDim.x + threadIdx.x;
  if (i < nb) hist[i] += bsum[i >> 10];
}

__global__ __launch_bounds__(256) void scatter_coarse(
    const int* __restrict__ src, const int* __restrict__ dst,
    const int* __restrict__ S, int2* __restrict__ epair, int E, int nbuck) {
  __shared__ int lb[1024];
  int t = threadIdx.x, blk = blockIdx.x;
  for (int i = t; i < nbuck; i += 256) lb[i] = S[i * NB_SORT + blk];
  __syncthreads();
  int ch = (E + NB_SORT - 1) / NB_SORT;
  int lo = blk * ch, hi = min(E, lo + ch);
  for (int e = lo + t; e < hi; e += 256) {
    int d = dst[e];
    int pos = atomicAdd(&lb[d >> 6], 1);
    epair[pos] = make_int2(src[e], d);
  }
}

__global__ __launch_bounds__(256) void fine_sort(
    const int2* __restrict__ epair, const int* __restrict__ S,
    int* __restrict__ ssrc, int* __restrict__ endoff, int E, int nbuck,
    int N) {
  __shared__ int fh[64];
  __shared__ int cur[64];
  int b = blockIdx.x, t = threadIdx.x;
  int bstart = S[b * NB_SORT];
  int bend = (b + 1 < nbuck) ? S[(b + 1) * NB_SORT] : E;
  if (t < 64) fh[t] = 0;
  __syncthreads();
  for (int e = bstart + t; e < bend; e += 256)
    atomicAdd(&fh[epair[e].y & 63], 1);
  __syncthreads();
  if (t < 64) {
    int v = fh[t];
    int incl = v;
#pragma unroll
    for (int off = 1; off < 64; off <<= 1) {
      int u = __shfl_up(incl, off, 64);
      if (t >= off) incl += u;
    }
    cur[t] = incl - v;
    int d = b * 64 + t;
    if (d < N) endoff[d] = bstart + incl;
  }
  __syncthreads();
  for (int e = bstart + t; e < bend; e += 256) {
    int2 p = epair[e];
    int pos = atomicAdd(&cur[p.y & 63], 1);
    ssrc[bstart + pos] = p.x;
  }
}

// ============ prep: quantize + node props + self-loop agg init ============
__global__ __launch_bounds__(256) void prep_x(const float* __restrict__ x,
                                              signed char* __restrict__ qx,
                                              float4* __restrict__ nprop,
                                              float* __restrict__ agg,
                                              int N) {
  int node = (int)((blockIdx.x * blockDim.x + threadIdx.x) >> 6);
  int lane = threadIdx.x & 63;
  if (node >= N) return;
  float2 v = *(const float2*)(x + (size_t)node * 128 + lane * 2);
  float ax = fabsf(v.x), ay = fabsf(v.y);
  float mx = wave_reduce_max(fmaxf(ax, ay));
  float l1 = wave_reduce_sum(ax + ay);
  float ss = wave_reduce_sum(v.x * v.x + v.y * v.y);
  float s = mx * (1.0f / 127.0f);
  float inv = (mx > 0.f) ? 127.0f / mx : 0.f;
  int q0 = clampq(v.x * inv), q1 = clampq(v.y * inv);
  unsigned short w = (unsigned short)((q0 & 0xff) | ((q1 & 0xff) << 8));
  ((unsigned short*)(qx + (size_t)node * 128))[lane] = w;
  float l1q = s * wave_reduce_sum((float)(abs(q0) + abs(q1)));
  bool sp = ss > 0.5f * fmaxf(ss, EPS);
  *(float2*)(agg + (size_t)node * 128 + lane * 2) =
      sp ? v : make_float2(0.f, 0.f);
  if (lane == 0)
    nprop[node] = make_float4(sqrtf(ss), s, fmaxf(l1, l1q), 0.f);
}

__global__ __launch_bounds__(256) void prep_h(const float* __restrict__ h,
                                              signed char* __restrict__ qh,
                                              float4* __restrict__ nprop,
                                              float* __restrict__ agg,
                                              int N) {
  int node = (int)((blockIdx.x * blockDim.x + threadIdx.x) >> 6);
  int lane = threadIdx.x & 63;
  if (node >= N) return;
  float4 v = *(const float4*)(h + (size_t)node * 256 + lane * 4);
  float ax = fabsf(v.x), ay = fabsf(v.y), az = fabsf(v.z), aw = fabsf(v.w);
  float mx = wave_reduce_max(fmaxf(fmaxf(ax, ay), fmaxf(az, aw)));
  float l1 = wave_reduce_sum(ax + ay + az + aw);
  float ss = wave_reduce_sum(dot4(v, v));
  float s = mx * (1.0f / 127.0f);
  float inv = (mx > 0.f) ? 127.0f / mx : 0.f;
  int q0 = clampq(v.x * inv), q1 = clampq(v.y * inv);
  int q2 = clampq(v.z * inv), q3 = clampq(v.w * inv);
  int w = (q0 & 0xff) | ((q1 & 0xff) << 8) | ((q2 & 0xff) << 16) | (q3 << 24);
  ((int*)(qh + (size_t)node * 256))[lane] = w;
  float l1q = s * wave_reduce_sum((float)(abs(q0) + abs(q1) + abs(q2) + abs(q3)));
  bool sp = ss > 0.5f * fmaxf(ss, EPS);
  *(float4*)(agg + (size_t)node * 256 + lane * 4) =
      sp ? v : make_float4(0.f, 0.f, 0.f, 0.f);
  if (lane == 0)
    nprop[node] = make_float4(sqrtf(ss), s, fmaxf(l1, l1q), 0.f);
}

// ====== conv, lane-per-edge: one 512-thread block per 64-node bucket ======
template <int D>
__global__ __launch_bounds__(512) void conv_lpe(
    const float* __restrict__ xf, const signed char* __restrict__ qt,
    const float4* __restrict__ nprop, const int* __restrict__ ssrc,
    const int* __restrict__ endoff, float* __restrict__ agg, int N) {
  constexpr int RB = D + 16;  // padded LDS row bytes
  constexpr int NG = D / 16;  // int4 chunks per row
  constexpr int V = D / 64;   // fp32 elems per lane (exact path)
  __shared__ signed char qtile[64 * RB];
  __shared__ float4 npd[64];
  __shared__ int eoff[65];
  const int tid = threadIdx.x;
  const int lane = tid & 63;
  const int n0 = blockIdx.x * 64;

  if (tid < 65) {
    int idx = n0 - 1 + tid;
    eoff[tid] = (idx < 0) ? 0 : endoff[min(idx, N - 1)];
  }
  if (tid >= 64 && tid < 128) {
    int i = tid - 64;
    int n = n0 + i;
    npd[i] = (n < N) ? nprop[n] : make_float4(0.f, 0.f, 0.f, 0.f);
  }
  for (int j = tid; j < 64 * NG; j += 512) {
    int r = j / NG, c = j % NG;
    int n = n0 + r;
    int4 v = (n < N) ? *(const int4*)(qt + (size_t)n * D + c * 16)
                     : make_int4(0, 0, 0, 0);
    *(int4*)(qtile + r * RB + c * 16) = v;
  }
  __syncthreads();  // qtile/npd/eoff ready

  const int bstart = eoff[0];
  const int bend = eoff[64];

  for (int base = bstart; base < bend; base += 512) {
    int e0 = base + tid;
    bool valid = e0 < bend;
    int s = valid ? ssrc[e0] : 0;
    float4 nps = valid ? nprop[s] : make_float4(0.f, 0.f, 0.f, 0.f);
    int lo = 0, hi = 63;
#pragma unroll
    for (int it = 0; it < 6; ++it) {
      int mid = (lo + hi) >> 1;
      if (e0 >= eoff[mid + 1]) lo = mid + 1; else hi = mid;
    }
    const int dloc = lo;
    float4 npdl = npd[dloc];
    const signed char* srow = qt + (size_t)s * D;
    const signed char* drow = qtile + dloc * RB;
    int id = 0;
#pragma unroll
    for (int g = 0; g < NG; ++g) {
      int4 a = *(const int4*)(srow + g * 16);
      int4 bq = *(const int4*)(drow + g * 16);
      id = sdot4i(a.x, bq.x, id);
      id = sdot4i(a.y, bq.y, id);
      id = sdot4i(a.z, bq.z, id);
      id = sdot4i(a.w, bq.w, id);
    }
    float denom = fmaxf(nps.x * npdl.x, EPS);
    float thr = 0.5f * denom;
    float approx = (nps.y * npdl.y) * (float)id;
    float m = 0.5002f * (nps.y * npdl.z + npdl.y * nps.z) + 2e-6f * denom + 1e-7f;
    bool maybe = valid && (approx > thr - m);
    unsigned long long mask = __ballot(maybe);
    while (mask) {
      int ln = __ffsll((long long)mask) - 1;
      mask &= mask - 1;
      int es = __shfl(s, ln);
      int dl = __shfl(dloc, ln);
      float nsx = __shfl(nps.x, ln);
      int dn = n0 + dl;
      float sv[V], dvv[V];
      if constexpr (V == 2) {
        float2 a = *(const float2*)(xf + (size_t)es * D + lane * 2);
        float2 b = *(const float2*)(xf + (size_t)dn * D + lane * 2);
        sv[0] = a.x; sv[1] = a.y; dvv[0] = b.x; dvv[1] = b.y;
      } else {
        float4 a = *(const float4*)(xf + (size_t)es * D + lane * 4);
        float4 b = *(const float4*)(xf + (size_t)dn * D + lane * 4);
        sv[0] = a.x; sv[1] = a.y; sv[2] = a.z; sv[3] = a.w;
        dvv[0] = b.x; dvv[1] = b.y; dvv[2] = b.z; dvv[3] = b.w;
      }
      float dx = 0.f;
#pragma unroll
      for (int q = 0; q < V; ++q) dx += sv[q] * dvv[q];
      dx = wave_reduce_sum(dx);
      float ndx = npd[dl].x;
      if (dx > 0.5f * fmaxf(nsx * ndx, EPS)) {
        float* arow = agg + (size_t)dn * D + lane * V;
#pragma unroll
        for (int q = 0; q < V; ++q) atomicAdd(&arow[q], sv[q]);
      }
    }
  }
}

// ---------------- GEMM1: h = relu(A @ W^T + b), 128x128 tile --------------
// LDS padded +4 (keeps float4 reads aligned; read banks conflict-free) and
// staging remapped so each wave writes 16 consecutive rows x kq-parity:
// bank = (16*(kq%2)+4j+row)%32 covers all 32 banks -> 2-way max (free).
template <int BM, int BN, int BK, int TM, bool RELU>
__global__ __launch_bounds__(256) void gemm_v2(
    const float* __restrict__ A, const float* __restrict__ W,
    const float* __restrict__ bias, float* __restrict__ C,
    int M, int N, int K) {
  constexpr int NTX = BN / 8;
  constexpr int NTY = 256 / NTX;
  static_assert(BM == NTY * TM, "tile shape");
  constexpr int KQ = BK / 4;
  constexpr int L4A = BM * KQ / 256;
  constexpr int L4B = BN * KQ / 256;
  constexpr int PM = BM + 4;
  constexpr int PN = BN + 4;
  __shared__ float As[BK][PM];
  __shared__ float Bs[BK][PN];
  const int tid = threadIdx.x;
  const int m0 = blockIdx.x * BM;
  const int n0 = blockIdx.y * BN;
  const int tx = tid % NTX;
  const int ty = tid / NTX;
  const int ms = ty * TM;
  const int ns = tx * 4;
  float acc[TM][8] = {};
  for (int k0 = 0; k0 < K; k0 += BK) {
#pragma unroll
    for (int t = 0; t < L4A; ++t) {
      int f = tid + t * 256;
      int row = (f >> 2) % BM;
      int kq = (f & 3) + 4 * (f / (4 * BM));
      int gm = m0 + row;
      float4 a = (gm < M) ? *(const float4*)&A[(size_t)gm * K + k0 + kq * 4]
                          : make_float4(0.f, 0.f, 0.f, 0.f);
      As[kq * 4 + 0][row] = a.x; As[kq * 4 + 1][row] = a.y;
      As[kq * 4 + 2][row] = a.z; As[kq * 4 + 3][row] = a.w;
    }
#pragma unroll
    for (int t = 0; t < L4B; ++t) {
      int f = tid + t * 256;
      int row = (f >> 2) % BN;
      int kq = (f & 3) + 4 * (f / (4 * BN));
      float4 b = *(const float4*)&W[(size_t)(n0 + row) * K + k0 + kq * 4];
      Bs[kq * 4 + 0][row] = b.x; Bs[kq * 4 + 1][row] = b.y;
      Bs[kq * 4 + 2][row] = b.z; Bs[kq * 4 + 3][row] = b.w;
    }
    __syncthreads();
#pragma unroll
    for (int kk = 0; kk < BK; ++kk) {
      float av[TM];
#pragma unroll
      for (int i = 0; i < TM / 4; ++i) {
        float4 t = *(const float4*)&As[kk][ms + i * 4];
        av[i * 4 + 0] = t.x; av[i * 4 + 1] = t.y;
        av[i * 4 + 2] = t.z; av[i * 4 + 3] = t.w;
      }
      float4 b0 = *(const float4*)&Bs[kk][ns];
      float4 b1 = *(const float4*)&Bs[kk][ns + BN / 2];
      float bv[8] = {b0.x, b0.y, b0.z, b0.w, b1.x, b1.y, b1.z, b1.w};
#pragma unroll
      for (int i = 0; i < TM; ++i)
#pragma unroll
        for (int j = 0; j < 8; ++j) acc[i][j] += av[i] * bv[j];
    }
    __syncthreads();
  }
  float4 bb0 = *(const float4*)&bias[n0 + ns];
  float4 bb1 = *(const float4*)&bias[n0 + BN / 2 + ns];
  float bv[8] = {bb0.x, bb0.y, bb0.z, bb0.w, bb1.x, bb1.y, bb1.z, bb1.w};
#pragma unroll
  for (int i = 0; i < TM; ++i) {
    int gm = m0 + ms + i;
    if (gm >= M) continue;
    float t[8];
#pragma unroll
    for (int j = 0; j < 8; ++j) {
      t[j] = acc[i][j] + bv[j];
      if (RELU) t[j] = fmaxf(t[j], 0.f);
    }
#pragma unroll
    for (int grp = 0; grp < 2; ++grp) {
      float4 o = {t[grp * 4 + 0], t[grp * 4 + 1], t[grp * 4 + 2],
                  t[grp * 4 + 3]};
      *(float4*)&C[(size_t)gm * N + n0 + grp * (BN / 2) + ns] = o;
    }
  }
}

// ------- GEMM2 fused with log_softmax: out = lsm(A @ W^T + b), BN=64 ------
// Same conflict-free staging (pads 132/68, 16-row write mapping).
__global__ __launch_bounds__(256) void gemm2_lsm(
    const float* __restrict__ A, const float* __restrict__ W,
    const float* __restrict__ bias, float* __restrict__ out, int M, int K) {
  constexpr int BM = 128, BN = 64, BK = 32, TM = 4;
  constexpr int NTX = BN / 8;     // 8
  constexpr int KQ = BK / 4;      // 8
  constexpr int L4A = BM * KQ / 256;  // 4
  constexpr int L4B = BN * KQ / 256;  // 2
  constexpr int PM = BM + 4;      // 132
  constexpr int PN = BN + 4;      // 68
  __shared__ float smem[BM * 65];     // 8320 floats >= BK*PM + BK*PN (6400)
  float* As = smem;                   // [BK][PM]
  float* Bs = smem + BK * PM;         // [BK][PN]
  const int tid = threadIdx.x;
  const int m0 = blockIdx.x * BM;
  const int tx = tid % NTX;
  const int ty = tid / NTX;
  const int ms = ty * TM;
  const int ns = tx * 4;
  float acc[TM][8] = {};
  for (int k0 = 0; k0 < K; k0 += BK) {
#pragma unroll
    for (int t = 0; t < L4A; ++t) {
      int f = tid + t * 256;
      int row = (f >> 2) % BM;
      int kq = (f & 3) + 4 * (f / (4 * BM));
      int gm = m0 + row;
      float4 a = (gm < M) ? *(const float4*)&A[(size_t)gm * K + k0 + kq * 4]
                          : make_float4(0.f, 0.f, 0.f, 0.f);
      As[(kq * 4 + 0) * PM + row] = a.x; As[(kq * 4 + 1) * PM + row] = a.y;
      As[(kq * 4 + 2) * PM + row] = a.z; As[(kq * 4 + 3) * PM + row] = a.w;
    }
#pragma unroll
    for (int t = 0; t < L4B; ++t) {
      int f = tid + t * 256;
      int row = (f >> 2) % BN;
      int kq = (f & 3) + 4 * (f / (4 * BN));
      float4 b = *(const float4*)&W[(size_t)row * K + k0 + kq * 4];
      Bs[(kq * 4 + 0) * PN + row] = b.x; Bs[(kq * 4 + 1) * PN + row] = b.y;
      Bs[(kq * 4 + 2) * PN + row] = b.z; Bs[(kq * 4 + 3) * PN + row] = b.w;
    }
    __syncthreads();
#pragma unroll
    for (int kk = 0; kk < BK; ++kk) {
      float4 a4 = *(const float4*)&As[kk * PM + ms];
      float av[4] = {a4.x, a4.y, a4.z, a4.w};
      float4 b0 = *(const float4*)&Bs[kk * PN + ns];
      float4 b1 = *(const float4*)&Bs[kk * PN + ns + 32];
      float bv[8] = {b0.x, b0.y, b0.z, b0.w, b1.x, b1.y, b1.z, b1.w};
#pragma unroll
      for (int i = 0; i < TM; ++i)
#pragma unroll
        for (int j = 0; j < 8; ++j) acc[i][j] += av[i] * bv[j];
    }
    __syncthreads();
  }
  float4 bb0 = *(const float4*)&bias[ns];
  float4 bb1 = *(const float4*)&bias[32 + ns];
  float bv[8] = {bb0.x, bb0.y, bb0.z, bb0.w, bb1.x, bb1.y, bb1.z, bb1.w};
#pragma unroll
  for (int i = 0; i < TM; ++i) {
    int row = ms + i;
#pragma unroll
    for (int grp = 0; grp < 2; ++grp)
#pragma unroll
      for (int j = 0; j < 4; ++j)
        smem[row * 65 + grp * 32 + ns + j] = acc[i][grp * 4 + j] + bv[grp * 4 + j];
  }
  __syncthreads();
  int w = tid >> 6, lane = tid & 63;
  for (int r = w; r < BM; r += 4) {
    int gm = m0 + r;
    if (gm >= M) continue;
    float v = smem[r * 65 + lane];
    float mx = wave_reduce_max(v);
    float e = expf(v - mx);
    float sm = wave_reduce_sum(e);
    out[(size_t)gm * 64 + lane] = v - mx - logf(sm);
  }
}

extern "C" void kernel_launch(void* const* d_in, const int* in_sizes, int n_in,
                              void* d_out, int out_size, void* d_ws,
                              size_t ws_size, hipStream_t stream) {
  const float* x  = (const float*)d_in[0];
  const int* eidx = (const int*)d_in[1];
  const float* W1 = (const float*)d_in[2];
  const float* b1 = (const float*)d_in[3];
  const float* W2 = (const float*)d_in[4];
  const float* b2 = (const float*)d_in[5];
  float* out = (float*)d_out;

  const int N = in_sizes[0] / 128;  // 50000
  const int E = in_sizes[1] / 2;    // 800000
  const int* src = eidx;
  const int* dst = eidx + E;

  const int nbuck = (N + 63) / 64;         // 782
  const int ntot = nbuck * NB_SORT;        // 200192
  const int nblk2 = (ntot + 1023) / 1024;  // 196

  float* agg    = (float*)d_ws;
  float* h      = agg + (size_t)N * 256;
  float4* npx   = (float4*)(h + (size_t)N * 256);
  float4* nph   = npx + N;
  int* S        = (int*)(nph + N);
  int* bsum     = S + ntot;
  int* ssrc     = bsum + 256;
  int* endoff   = ssrc + E;
  signed char* qh = (signed char*)(endoff + N);
  int2* epair   = (int2*)h;                              // overlap (6.4 MB)
  signed char* qx = (signed char*)(h + (size_t)N * 64);  // overlap (6.4 MB)

  // ---- build CSR (by dst) with LDS-only atomics ----
  hist_coarse<<<NB_SORT, 256, 0, stream>>>(dst, S, E, nbuck);
  scan_local<<<nblk2, 256, 0, stream>>>(S, bsum, ntot);
  scan_bsum<<<1, 256, 0, stream>>>(bsum, nblk2);
  add_bsum<<<(ntot + 255) / 256, 256, 0, stream>>>(S, bsum, ntot);
  scatter_coarse<<<NB_SORT, 256, 0, stream>>>(src, dst, S, epair, E, nbuck);
  fine_sort<<<nbuck, 256, 0, stream>>>(epair, S, ssrc, endoff, E, nbuck, N);

  // ---- layer 1 (D=128) ----
  prep_x<<<(N + 3) / 4, 256, 0, stream>>>(x, qx, npx, agg, N);
  conv_lpe<128><<<nbuck, 512, 0, stream>>>(x, qx, npx, ssrc, endoff, agg, N);
  gemm_v2<128, 128, 32, 8, true>
      <<<dim3((N + 127) / 128, 2), 256, 0, stream>>>(agg, W1, b1, h, N, 256,
                                                     128);

  // ---- layer 2 (D=256) ----
  prep_h<<<(N + 3) / 4, 256, 0, stream>>>(h, qh, nph, agg, N);
  conv_lpe<256><<<nbuck, 512, 0, stream>>>(h, qh, nph, ssrc, endoff, agg, N);
  gemm2_lsm<<<dim3((N + 127) / 128), 256, 0, stream>>>(agg, W2, b2, out, N,
                                                       256);
}